// Round 13
// baseline (1549.423 us; speedup 1.0000x reference)
//
#include <hip/hip_runtime.h>
#include <hip/hip_bf16.h>

typedef unsigned short u16;
typedef unsigned int u32;

#define NN 8192
#define PXC 2560
#define MAXD 36
#define GY 96

typedef __attribute__((ext_vector_type(8))) short bf16x8;
typedef __attribute__((ext_vector_type(4))) float f32x4;

// ---------------- workspace layout (bytes) ----------------
static constexpr size_t SZ_PX  = (size_t)(NN + 1) * PXC * 2;
static constexpr size_t SZ_ACC = (size_t)(NN + 1) * 512 * 4;
static constexpr size_t SZ_HB  = (size_t)(NN + 1) * 512 * 2;
static constexpr size_t SZ_G   = (size_t)(NN + 1) * 1536 * 4;
static constexpr size_t SZ_NW  = (size_t)5242880 * 2;

static constexpr size_t OFF_PX    = 0;
static constexpr size_t OFF_QX    = OFF_PX + SZ_PX;
static constexpr size_t OFF_ACCH  = OFF_QX + SZ_PX;
static constexpr size_t OFF_ACCF  = OFF_ACCH + SZ_ACC;
static constexpr size_t OFF_ACCZ  = OFF_ACCF + SZ_ACC;
static constexpr size_t OFF_C     = OFF_ACCZ + SZ_ACC;         // c_all (chain), f32
static constexpr size_t OFF_HB    = OFF_C + SZ_ACC;            // h_all (chain), bf16
static constexpr size_t OFF_ZB    = OFF_HB + SZ_HB;            // chain ZB, bf16
static constexpr size_t OFF_G     = OFF_ZB + SZ_HB;            // per-node scratch / transient normalized inputs
static constexpr size_t OFF_NW    = OFF_G + SZ_G;
static constexpr size_t OFF_DEPTH = OFF_NW + SZ_NW;
static constexpr size_t OFF_ORDER = OFF_DEPTH + (size_t)NN * 4;
static constexpr size_t OFF_MISC  = OFF_ORDER + (size_t)NN * 4;
static constexpr size_t OFF_LVL   = OFF_MISC + 1024;
static constexpr size_t OFF_NB    = OFF_LVL + 512;
static constexpr size_t OFF_PN    = OFF_NB + 20480;
static constexpr size_t OFF_PMAX  = OFF_PN + (size_t)NN * 4;
static constexpr size_t WS_TOTAL  = OFF_PMAX + (size_t)128 * 512 * 4;

#define NW_CSWX  0
#define NW_CHWX  1310720
#define NW_CSWIO 2621440
#define NW_CSWFZ 3145728
#define NW_CSWUM 3670016
#define NW_CHWH  3932160
#define NW_CHWUM 4980736

#define NB_CSBX  0
#define NB_CSBIO 2560
#define NB_CSBFZ 3584
#define NB_CSBUM 4608
#define NB_CHBX  5120
#define NB_CHBH  7680
#define NB_CHBUM 9728

// ---------------- helpers ----------------
__device__ __forceinline__ float bfu(u16 u) { return __uint_as_float(((u32)u) << 16); }
__device__ __forceinline__ u16 f2bf(float f) {
    u32 u = __float_as_uint(f);
    u += 0x7fffu + ((u >> 16) & 1u);
    return (u16)(u >> 16);
}
__device__ __forceinline__ float sigf(float x) {
    x = fminf(fmaxf(x, -30.f), 30.f);
    return 1.f / (1.f + __expf(-x));
}
__device__ __forceinline__ float tanhq(float x) {
    x = fminf(fmaxf(x, -15.f), 15.f);
    return 1.f - 2.f / (__expf(2.f * x) + 1.f);
}
__device__ __forceinline__ bf16x8 cvt8(const float* p) {
    float4 a = *(const float4*)p;
    float4 b = *(const float4*)(p + 4);
    union { u32 u[4]; bf16x8 v; } r;
    r.u[0] = ((__float_as_uint(a.x) + 0x8000u) >> 16) | ((__float_as_uint(a.y) + 0x8000u) & 0xffff0000u);
    r.u[1] = ((__float_as_uint(a.z) + 0x8000u) >> 16) | ((__float_as_uint(a.w) + 0x8000u) & 0xffff0000u);
    r.u[2] = ((__float_as_uint(b.x) + 0x8000u) >> 16) | ((__float_as_uint(b.y) + 0x8000u) & 0xffff0000u);
    r.u[3] = ((__float_as_uint(b.z) + 0x8000u) >> 16) | ((__float_as_uint(b.w) + 0x8000u) & 0xffff0000u);
    return r.v;
}

// per-node scratch (G region, 1536 f32/node):
// cs: c -> f32 [n*1536 .. +512) ; h -> bf16 at u16 idx [n*3072+1024 .. +512)
// ch: si/so/sf -> f32 [n*1536 + {0,512,1024})

// ---------------- dtype detection ----------------
__global__ void k_detect(const u32* __restrict__ fin, const u32* __restrict__ pin,
                         int* __restrict__ fcnt, int* __restrict__ pcnt) {
    int i = blockIdx.x * 256 + threadIdx.x;
    if (i < 4096) {
        u32 w = fin[i];
        int e = (w >> 7) & 0xFF;
        if (w != 0u && e >= 0x70 && e <= 0x8F) atomicAdd(fcnt, 1);
    }
    if (i >= 1 && i < 4096) {
        if (pin[2 * i - 1] != 0u) atomicAdd(pcnt, 1);
    }
}

// fused: parent normalize + depth chase + sentinel-row init
__global__ void k_pnorm_depth(const u32* __restrict__ pin, const int* __restrict__ pcnt,
                              int* __restrict__ pnorm, int* __restrict__ depth,
                              u16* __restrict__ HB, float* __restrict__ Call) {
    int i = blockIdx.x * 256 + threadIdx.x;
    if (i < 512) {
        HB[(size_t)NN * 512 + i] = 0;
        Call[(size_t)NN * 512 + i] = 0.f;
    }
    if (i >= NN) return;
    bool is64 = (*pcnt < 100);
    int p = (int)(is64 ? pin[2 * i] : pin[i]);
    pnorm[i] = p;
    int d = 0;
    while (p != NN && p >= 0 && p < NN && d < 9000) {
        d++;
        p = (int)(is64 ? pin[2 * p] : pin[p]);
    }
    depth[i] = d;
}

// fused hist + scan + scatter, single block
__global__ __launch_bounds__(1024) void k_levels(const int* __restrict__ depth,
                                                 int* __restrict__ lvl, int* __restrict__ order) {
    __shared__ int cnts[64];
    __shared__ int cur[64];
    int t = threadIdx.x;
    if (t < 64) cnts[t] = 0;
    __syncthreads();
    for (int i = t; i < NN; i += 1024) {
        int d = depth[i]; if (d > 63) d = 63;
        atomicAdd(&cnts[d], 1);
    }
    __syncthreads();
    if (t == 0) {
        int s = 0; lvl[0] = 0;
        for (int d = 0; d < 64; ++d) { cur[d] = s; s += cnts[d]; lvl[d + 1] = s; }
    }
    __syncthreads();
    for (int i = t; i < NN; i += 1024) {
        int d = depth[i]; if (d > 63) d = 63;
        int pos = atomicAdd(&cur[d], 1);
        order[pos] = i;
    }
}

struct NormSrcs { const void* p[15]; };
// segs 0-7 (inputs + weights) only needed when f32; segs 8-14 (biases) always
__global__ __launch_bounds__(256) void k_norm_all(NormSrcs s, u16* __restrict__ NGI,
                                                  u16* __restrict__ NW, u16* __restrict__ NB,
                                                  const int* __restrict__ fcnt) {
    const int cum[16] = {0, 1048576, 1376256, 1703936, 1835008, 1966080, 2031616, 2293760,
                         2359296, 2359936, 2360192, 2360448, 2360576, 2361216, 2361728, 2361856};
    const int dof[15] = {0, NW_CSWX / 4, NW_CHWX / 4, NW_CSWIO / 4, NW_CSWFZ / 4, NW_CSWUM / 4,
                         NW_CHWH / 4, NW_CHWUM / 4, NB_CSBX / 4, NB_CSBIO / 4, NB_CSBFZ / 4,
                         NB_CSBUM / 4, NB_CHBX / 4, NB_CHBH / 4, NB_CHBUM / 4};
    bool isbf = (*fcnt > 2048);
    int total = 2361856;
    int istart = isbf ? cum[8] : 0;       // bf16: only biases need copying
    for (int i = istart + blockIdx.x * 256 + threadIdx.x; i < total; i += gridDim.x * 256) {
        int seg = 0;
#pragma unroll
        for (int k = 1; k < 15; ++k) if (i >= cum[k]) seg = k;
        int off = i - cum[seg];
        u16* dbase = (seg == 0) ? NGI : (seg < 8 ? NW : NB);
        ushort4* dst = (ushort4*)dbase + dof[seg] + off;
        if (isbf) {
            *dst = ((const ushort4*)s.p[seg])[off];
        } else {
            float4 v = ((const float4*)s.p[seg])[off];
            ushort4 o; o.x = f2bf(v.x); o.y = f2bf(v.y); o.z = f2bf(v.z); o.w = f2bf(v.w);
            *dst = o;
        }
    }
}

// ---------------- input-projection GEMM: grid (10, 128, 2), A-tile staged in LDS ----------------
#define ASTR 528   // u16 row stride: 1056B (16B-aligned), 264 dw -> 4-way bank alias only
__global__ __launch_bounds__(256) void k_gemm_in(
    const u16* __restrict__ Ao, const u16* __restrict__ An,
    const u16* __restrict__ Wcs_o, const u16* __restrict__ Wcs_n,
    const u16* __restrict__ Wch_o, const u16* __restrict__ Wch_n,
    const u16* __restrict__ bcs, const u16* __restrict__ bch,
    u16* __restrict__ Ccs, u16* __restrict__ Cch,
    const int* __restrict__ fcnt)
{
    __shared__ __align__(16) u16 AS[64 * ASTR];
    bool isbf = (*fcnt > 2048);
    int z = blockIdx.z;
    const u16* A = isbf ? Ao : An;
    const u16* W = z ? (isbf ? Wch_o : Wch_n) : (isbf ? Wcs_o : Wcs_n);
    const u16* bias = z ? bch : bcs;
    u16* C = z ? Cch : Ccs;

    int m0 = blockIdx.y * 64;
    // cooperative A-tile load: 64 rows x 512 cols (each thread 16 x 16B chunks)
    for (int e = threadIdx.x; e < 64 * 64; e += 256) {
        int row = e >> 6, c8 = e & 63;
        *(uint4*)&AS[row * ASTR + c8 * 8] = *(const uint4*)(A + (size_t)(m0 + row) * 512 + c8 * 8);
    }
    __syncthreads();

    int wv = threadIdx.x >> 6;
    int lane = threadIdx.x & 63;
    int r = lane & 15, q = lane >> 4;
    int n0 = blockIdx.x * 256 + wv * 64;
    const u16* pb[4];
#pragma unroll
    for (int jt = 0; jt < 4; ++jt) pb[jt] = W + (size_t)(n0 + jt * 16 + r) * 512 + q * 8;
    f32x4 acc[4][4] = {};
#pragma unroll 2
    for (int k0 = 0; k0 < 512; k0 += 32) {
        bf16x8 a[4], b[4];
#pragma unroll
        for (int mi = 0; mi < 4; ++mi)
            a[mi] = *(const bf16x8*)&AS[(mi * 16 + r) * ASTR + k0 + q * 8];
#pragma unroll
        for (int jt = 0; jt < 4; ++jt) b[jt] = *(const bf16x8*)(pb[jt] + k0);
#pragma unroll
        for (int mi = 0; mi < 4; ++mi)
#pragma unroll
            for (int jt = 0; jt < 4; ++jt)
                acc[mi][jt] = __builtin_amdgcn_mfma_f32_16x16x32_bf16(a[mi], b[jt], acc[mi][jt], 0, 0, 0);
    }
#pragma unroll
    for (int jt = 0; jt < 4; ++jt) {
        int c = n0 + jt * 16 + r;
        float bv = bfu(bias[c]);
#pragma unroll
        for (int mi = 0; mi < 4; ++mi) {
            size_t b0 = (size_t)(m0 + mi * 16 + q * 4) * PXC + c;
#pragma unroll
            for (int i = 0; i < 4; ++i)
                C[b0 + (size_t)i * PXC] = f2bf(acc[mi][jt][i] + bv);
        }
    }
}

// ---------------- combined phase-1: grid (32, GY, 2), plane = blockIdx.z ----------------
__global__ __launch_bounds__(64) void comb_s1(
    int dcs, int dch,
    const int* __restrict__ order, const int* __restrict__ lvl, const int* __restrict__ parent,
    float* acc_h, const float* __restrict__ acc_fc, const float* __restrict__ acc_zc,
    const u16* __restrict__ Wio_o, const u16* __restrict__ Wio_n,
    const u16* __restrict__ Wum_o, const u16* __restrict__ Wum_n,
    const u16* __restrict__ bio, const u16* __restrict__ bum,
    const u16* __restrict__ px,
    const u16* __restrict__ HB, const float* __restrict__ Call,
    const u16* __restrict__ Wh_o, const u16* __restrict__ Wh_n,
    const u16* __restrict__ bh,
    const u16* __restrict__ qx, u16* __restrict__ ZB,
    float* __restrict__ G,
    void* __restrict__ outv, const int* __restrict__ fcnt)
{
    bool isbf = (*fcnt > 2048);
    int lane = threadIdx.x;
    int r = lane & 15, q = lane >> 4;
    int cg = blockIdx.x;
    int c0 = cg * 16;
    int col = c0 + r;
    u16* Gh = (u16*)G;

    if (blockIdx.z == 0) {
        int d = dcs;
        int start = lvl[d], cnt = lvl[d + 1] - start;
        if (cnt <= 0) return;
        int ntiles = (cnt + 15) >> 4;
        const u16* Wio = isbf ? Wio_o : Wio_n;
        const u16* Wum = isbf ? Wum_o : Wum_n;
        const u16* pbi = Wio + (size_t)(c0 + r) * 512 + q * 8;
        const u16* pbo = Wio + (size_t)(512 + c0 + r) * 512 + q * 8;
        const u16* pbu = Wum + (size_t)(c0 + r) * 512 + q * 8;
        for (int tile = blockIdx.y; tile < ntiles; tile += GY) {
            int tr = tile * 16 + r;
            int nodeR = (tr < cnt) ? order[start + tr] : NN;
            const float* pah = acc_h + (size_t)nodeR * 512 + q * 8;
            const float* paz = acc_zc + (size_t)nodeR * 512 + q * 8;
            // 3 gates x K-split 2 = 6 independent chains of depth 8
            f32x4 ai0 = {}, ai1 = {}, ao0 = {}, ao1 = {}, au0 = {}, au1 = {};
#pragma unroll 4
            for (int ko = 0; ko < 256; ko += 32) {
                bf16x8 ah0 = cvt8(pah + ko);
                bf16x8 ah1 = cvt8(pah + 256 + ko);
                bf16x8 az0 = cvt8(paz + ko);
                bf16x8 az1 = cvt8(paz + 256 + ko);
                ai0 = __builtin_amdgcn_mfma_f32_16x16x32_bf16(ah0, *(const bf16x8*)(pbi + ko), ai0, 0, 0, 0);
                ai1 = __builtin_amdgcn_mfma_f32_16x16x32_bf16(ah1, *(const bf16x8*)(pbi + 256 + ko), ai1, 0, 0, 0);
                ao0 = __builtin_amdgcn_mfma_f32_16x16x32_bf16(ah0, *(const bf16x8*)(pbo + ko), ao0, 0, 0, 0);
                ao1 = __builtin_amdgcn_mfma_f32_16x16x32_bf16(ah1, *(const bf16x8*)(pbo + 256 + ko), ao1, 0, 0, 0);
                au0 = __builtin_amdgcn_mfma_f32_16x16x32_bf16(az0, *(const bf16x8*)(pbu + ko), au0, 0, 0, 0);
                au1 = __builtin_amdgcn_mfma_f32_16x16x32_bf16(az1, *(const bf16x8*)(pbu + 256 + ko), au1, 0, 0, 0);
            }
            f32x4 ai = ai0 + ai1, ao = ao0 + ao1, au = au0 + au1;
            float bi_ = bfu(bio[col]), bo_ = bfu(bio[512 + col]), bu_ = bfu(bum[col]);
#pragma unroll
            for (int i2 = 0; i2 < 4; ++i2) {
                int ti = tile * 16 + q * 4 + i2;
                if (ti >= cnt) continue;
                int ni = order[start + ti];
                int p = parent[ni];
                size_t pxb = (size_t)ni * PXC, nb = (size_t)ni * 512;
                float ig = sigf(bfu(px[pxb + col]) + ai[i2] + bi_);
                float og = sigf(bfu(px[pxb + 1024 + col]) + ao[i2] + bo_);
                float uu = tanhq(bfu(px[pxb + 2048 + col]) + au[i2] + bu_);
                float cc = ig * uu + acc_fc[nb + col];
                float h = og * tanhq(cc);
                G[(size_t)ni * 1536 + col] = cc;
                Gh[(size_t)ni * 3072 + 1024 + col] = f2bf(h);
                atomicAdd(&acc_h[(size_t)p * 512 + col], h);
                if (ni == 0) {
                    if (isbf) ((u16*)outv)[col] = f2bf(h);
                    else ((float*)outv)[col] = h;
                }
            }
        }
    } else {
        int d = dch;
        int start = lvl[d], cnt = lvl[d + 1] - start;
        if (cnt <= 0) return;
        int ntiles = (cnt + 15) >> 4;
        const u16* Wh = isbf ? Wh_o : Wh_n;
        const u16* pbi = Wh + (size_t)(c0 + r) * 512 + q * 8;
        const u16* pbo = Wh + (size_t)(512 + c0 + r) * 512 + q * 8;
        const u16* pbf = Wh + (size_t)(1024 + c0 + r) * 512 + q * 8;
        const u16* pbz = Wh + (size_t)(1536 + c0 + r) * 512 + q * 8;
        for (int tile = blockIdx.y; tile < ntiles; tile += GY) {
            int tr = tile * 16 + r;
            int nod = (tr < cnt) ? order[start + tr] : -1;
            int prow = (nod < 0) ? NN : parent[nod];
            const u16* pa = HB + (size_t)prow * 512 + q * 8;
            // 4 gates x K-split 2 = 8 chains of depth 8
            f32x4 gi0 = {}, gi1 = {}, go0 = {}, go1 = {}, gf0 = {}, gf1 = {}, gz0 = {}, gz1 = {};
#pragma unroll 4
            for (int ko = 0; ko < 256; ko += 32) {
                bf16x8 a0 = *(const bf16x8*)(pa + ko);
                bf16x8 a1 = *(const bf16x8*)(pa + 256 + ko);
                gi0 = __builtin_amdgcn_mfma_f32_16x16x32_bf16(a0, *(const bf16x8*)(pbi + ko), gi0, 0, 0, 0);
                gi1 = __builtin_amdgcn_mfma_f32_16x16x32_bf16(a1, *(const bf16x8*)(pbi + 256 + ko), gi1, 0, 0, 0);
                go0 = __builtin_amdgcn_mfma_f32_16x16x32_bf16(a0, *(const bf16x8*)(pbo + ko), go0, 0, 0, 0);
                go1 = __builtin_amdgcn_mfma_f32_16x16x32_bf16(a1, *(const bf16x8*)(pbo + 256 + ko), go1, 0, 0, 0);
                gf0 = __builtin_amdgcn_mfma_f32_16x16x32_bf16(a0, *(const bf16x8*)(pbf + ko), gf0, 0, 0, 0);
                gf1 = __builtin_amdgcn_mfma_f32_16x16x32_bf16(a1, *(const bf16x8*)(pbf + 256 + ko), gf1, 0, 0, 0);
                gz0 = __builtin_amdgcn_mfma_f32_16x16x32_bf16(a0, *(const bf16x8*)(pbz + ko), gz0, 0, 0, 0);
                gz1 = __builtin_amdgcn_mfma_f32_16x16x32_bf16(a1, *(const bf16x8*)(pbz + 256 + ko), gz1, 0, 0, 0);
            }
            f32x4 gi = gi0 + gi1, go = go0 + go1, gf = gf0 + gf1, gz = gz0 + gz1;
            float bi_ = bfu(bh[col]), bo_ = bfu(bh[512 + col]);
            float bf_ = bfu(bh[1024 + col]), bz_ = bfu(bh[1536 + col]);
#pragma unroll
            for (int i2 = 0; i2 < 4; ++i2) {
                int ti = tile * 16 + q * 4 + i2;
                if (ti >= cnt) continue;
                int ni = order[start + ti];
                int p = parent[ni];
                size_t qb = (size_t)ni * PXC, gb = (size_t)ni * 1536, nb = (size_t)ni * 512;
                float si = sigf(bfu(qx[qb + col]) + gi[i2] + bi_);
                float so = sigf(bfu(qx[qb + 512 + col]) + go[i2] + bo_);
                float sf = sigf(bfu(qx[qb + 1024 + col]) + gf[i2] + bf_);
                float zg = sigf(bfu(qx[qb + 1536 + col]) + gz[i2] + bz_);
                G[gb + col] = si;
                G[gb + 512 + col] = so;
                G[gb + 1024 + col] = sf;
                ZB[nb + col] = f2bf(zg * tanhq(Call[(size_t)p * 512 + col]));
            }
        }
    }
}

// ---------------- combined phase-2 (K-split accumulator chains) ----------------
__global__ __launch_bounds__(64) void comb_s2(
    int dcs, int dch,
    const int* __restrict__ order, const int* __restrict__ lvl, const int* __restrict__ parent,
    const u16* __restrict__ Wfz_o, const u16* __restrict__ Wfz_n,
    const u16* __restrict__ bfz,
    const u16* __restrict__ px,
    float* __restrict__ acc_fc, float* __restrict__ acc_zc,
    const u16* __restrict__ ZB, const u16* __restrict__ qx,
    const u16* __restrict__ Wum_o, const u16* __restrict__ Wum_n,
    const u16* __restrict__ bum,
    float* __restrict__ Call, u16* __restrict__ HB,
    float* __restrict__ G, const int* __restrict__ fcnt)
{
    bool isbf = (*fcnt > 2048);
    int lane = threadIdx.x;
    int r = lane & 15, q = lane >> 4;
    int cg = blockIdx.x;
    int c0 = cg * 16;
    int col = c0 + r;
    const u16* Gh = (const u16*)G;

    if (blockIdx.z == 0) {
        int d = dcs;
        int start = lvl[d], cnt = lvl[d + 1] - start;
        if (cnt <= 0) return;
        int ntiles = (cnt + 15) >> 4;
        const u16* Wfz = isbf ? Wfz_o : Wfz_n;
        const u16* pbf = Wfz + (size_t)(c0 + r) * 512 + q * 8;
        const u16* pbz = Wfz + (size_t)(512 + c0 + r) * 512 + q * 8;
        for (int tile = blockIdx.y; tile < ntiles; tile += GY) {
            int tr = tile * 16 + r;
            int nodeR = (tr < cnt) ? order[start + tr] : NN;
            const u16* pa = Gh + (size_t)nodeR * 3072 + 1024 + q * 8;
            f32x4 af0 = {}, af1 = {}, az0 = {}, az1 = {};
#pragma unroll 4
            for (int ko = 0; ko < 256; ko += 32) {
                bf16x8 a0 = *(const bf16x8*)(pa + ko);
                bf16x8 a1 = *(const bf16x8*)(pa + 256 + ko);
                af0 = __builtin_amdgcn_mfma_f32_16x16x32_bf16(a0, *(const bf16x8*)(pbf + ko), af0, 0, 0, 0);
                az0 = __builtin_amdgcn_mfma_f32_16x16x32_bf16(a0, *(const bf16x8*)(pbz + ko), az0, 0, 0, 0);
                af1 = __builtin_amdgcn_mfma_f32_16x16x32_bf16(a1, *(const bf16x8*)(pbf + 256 + ko), af1, 0, 0, 0);
                az1 = __builtin_amdgcn_mfma_f32_16x16x32_bf16(a1, *(const bf16x8*)(pbz + 256 + ko), az1, 0, 0, 0);
            }
            f32x4 af = af0 + af1, az = az0 + az1;
            float bf_ = bfu(bfz[col]), bz_ = bfu(bfz[512 + col]);
#pragma unroll
            for (int i2 = 0; i2 < 4; ++i2) {
                int ti = tile * 16 + q * 4 + i2;
                if (ti >= cnt) continue;
                int ni = order[start + ti];
                int p = parent[ni];
                size_t pb = (size_t)p * 512, ppx = (size_t)p * PXC;
                float cT = G[(size_t)ni * 1536 + col];
                float f = sigf(bfu(px[ppx + 512 + col]) + af[i2] + bf_);
                atomicAdd(&acc_fc[pb + col], f * cT);
                float zf = sigf(bfu(px[ppx + 1536 + col]) + az[i2] + bz_);
                atomicAdd(&acc_zc[pb + col], zf * tanhq(cT));
            }
        }
    } else {
        int d = dch;
        int start = lvl[d], cnt = lvl[d + 1] - start;
        if (cnt <= 0) return;
        int ntiles = (cnt + 15) >> 4;
        const u16* Wum = isbf ? Wum_o : Wum_n;
        const u16* pbu = Wum + (size_t)(c0 + r) * 512 + q * 8;
        for (int tile = blockIdx.y; tile < ntiles; tile += GY) {
            int tr = tile * 16 + r;
            int nodeR = (tr < cnt) ? order[start + tr] : NN;
            const u16* pa = ZB + (size_t)nodeR * 512 + q * 8;
            f32x4 a0 = {}, a1 = {}, a2 = {}, a3 = {};
#pragma unroll 4
            for (int ko = 0; ko < 128; ko += 32) {
                a0 = __builtin_amdgcn_mfma_f32_16x16x32_bf16(*(const bf16x8*)(pa + ko),
                                                             *(const bf16x8*)(pbu + ko), a0, 0, 0, 0);
                a1 = __builtin_amdgcn_mfma_f32_16x16x32_bf16(*(const bf16x8*)(pa + 128 + ko),
                                                             *(const bf16x8*)(pbu + 128 + ko), a1, 0, 0, 0);
                a2 = __builtin_amdgcn_mfma_f32_16x16x32_bf16(*(const bf16x8*)(pa + 256 + ko),
                                                             *(const bf16x8*)(pbu + 256 + ko), a2, 0, 0, 0);
                a3 = __builtin_amdgcn_mfma_f32_16x16x32_bf16(*(const bf16x8*)(pa + 384 + ko),
                                                             *(const bf16x8*)(pbu + 384 + ko), a3, 0, 0, 0);
            }
            f32x4 au = (a0 + a1) + (a2 + a3);
            float bu_ = bfu(bum[col]);
#pragma unroll
            for (int i2 = 0; i2 < 4; ++i2) {
                int ti = tile * 16 + q * 4 + i2;
                if (ti >= cnt) continue;
                int ni = order[start + ti];
                int p = parent[ni];
                size_t qb = (size_t)ni * PXC, gb = (size_t)ni * 1536, nb = (size_t)ni * 512;
                float uu = tanhq(bfu(qx[qb + 2048 + col]) + au[i2] + bu_);
                float si = G[gb + col];
                float so = G[gb + 512 + col];
                float sf = G[gb + 1024 + col];
                float pc = Call[(size_t)p * 512 + col];
                float cc = si * uu + sf * pc;
                float h = so * tanhq(cc);
                Call[nb + col] = cc;
                HB[nb + col] = f2bf(h);
            }
        }
    }
}

// ---------------- final max reduce ----------------
__global__ __launch_bounds__(256) void k_maxA(const u16* __restrict__ HB, float* __restrict__ pmax) {
    int b = blockIdx.x, t = threadIdx.x;
    float m1 = -1e30f, m2 = -1e30f;
    for (int rr = b * 128; rr < b * 128 + 128; ++rr) {
        m1 = fmaxf(m1, bfu(HB[(size_t)rr * 512 + t]));
        m2 = fmaxf(m2, bfu(HB[(size_t)rr * 512 + t + 256]));
    }
    pmax[(size_t)b * 512 + t] = m1; pmax[(size_t)b * 512 + t + 256] = m2;
}
__global__ void k_maxB(const float* __restrict__ pmax, void* __restrict__ outv,
                       const int* __restrict__ fcnt) {
    int j = threadIdx.x;
    float m = -1e30f;
    for (int b = 0; b < 64; ++b) m = fmaxf(m, pmax[(size_t)b * 512 + j]);
    bool isbf = (*fcnt > 2048);
    if (isbf) ((u16*)outv)[512 + j] = f2bf(m);
    else ((float*)outv)[512 + j] = m;
}

__global__ void k_wsfail(u16* out) {
    int i = blockIdx.x * 256 + threadIdx.x;
    if (i < 1024) out[i] = f2bf(12345.f);
}

// ---------------- launch ----------------
extern "C" void kernel_launch(void* const* d_in, const int* in_sizes, int n_in,
                              void* d_out, int out_size, void* d_ws, size_t ws_size,
                              hipStream_t stream) {
    char* base = (char*)d_ws;
    u16* px = (u16*)(base + OFF_PX);
    u16* qx = (u16*)(base + OFF_QX);
    float* acc_h = (float*)(base + OFF_ACCH);
    float* acc_fc = (float*)(base + OFF_ACCF);
    float* acc_zc = (float*)(base + OFF_ACCZ);
    float* Call = (float*)(base + OFF_C);
    u16* HB = (u16*)(base + OFF_HB);
    u16* ZB = (u16*)(base + OFF_ZB);
    float* G = (float*)(base + OFF_G);
    u16* NGI = (u16*)(base + OFF_G);
    u16* NW = (u16*)(base + OFF_NW);
    int* depth = (int*)(base + OFF_DEPTH);
    int* order = (int*)(base + OFF_ORDER);
    int* counts = (int*)(base + OFF_MISC);
    int* fcnt = counts + 128;
    int* pcnt = counts + 129;
    int* lvl = (int*)(base + OFF_LVL);
    u16* NB = (u16*)(base + OFF_NB);
    int* pnorm = (int*)(base + OFF_PN);
    float* pmax = (float*)(base + OFF_PMAX);

    const u16* in_bf   = (const u16*)d_in[0];
    const u16* csWx_o  = (const u16*)d_in[2];
    const u16* csWio_o = (const u16*)d_in[4];
    const u16* csWfz_o = (const u16*)d_in[6];
    const u16* csWum_o = (const u16*)d_in[8];
    const u16* chWx_o  = (const u16*)d_in[10];
    const u16* chWh_o  = (const u16*)d_in[12];
    const u16* chWum_o = (const u16*)d_in[14];

    if (ws_size < WS_TOTAL) { k_wsfail<<<4, 256, 0, stream>>>((u16*)d_out); return; }

    hipMemsetAsync(base + OFF_MISC, 0, 1024, stream);
    hipMemsetAsync(base + OFF_ACCH, 0, 3 * SZ_ACC, stream);   // acc_h/fc/zc (+ sentinel rows)

    // dtype detect + fused setup
    k_detect<<<16, 256, 0, stream>>>((const u32*)d_in[0], (const u32*)d_in[1], fcnt, pcnt);
    k_pnorm_depth<<<32, 256, 0, stream>>>((const u32*)d_in[1], pcnt, pnorm, depth, HB, Call);
    k_levels<<<1, 1024, 0, stream>>>(depth, lvl, order);

    NormSrcs srcs;
    srcs.p[0] = d_in[0];  srcs.p[1] = d_in[2];  srcs.p[2] = d_in[10]; srcs.p[3] = d_in[4];
    srcs.p[4] = d_in[6];  srcs.p[5] = d_in[8];  srcs.p[6] = d_in[12]; srcs.p[7] = d_in[14];
    srcs.p[8] = d_in[3];  srcs.p[9] = d_in[5];  srcs.p[10] = d_in[7]; srcs.p[11] = d_in[9];
    srcs.p[12] = d_in[11]; srcs.p[13] = d_in[13]; srcs.p[14] = d_in[15];
    k_norm_all<<<2048, 256, 0, stream>>>(srcs, NGI, NW, NB, fcnt);

    // input projections — A-tile in LDS, 64m x 256n per block
    dim3 gg(PXC / 256, NN / 64, 2);
    k_gemm_in<<<gg, 256, 0, stream>>>(in_bf, NGI,
                                      csWx_o, NW + NW_CSWX, chWx_o, NW + NW_CHWX,
                                      NB + NB_CSBX, NB + NB_CHBX, px, qx, fcnt);

    // fused levels: dispatch i runs cs level (MAXD-1-i) and ch level (i)
    dim3 gl(32, GY, 2);
    for (int i = 0; i < MAXD; ++i) {
        int dcs = MAXD - 1 - i, dch = i;
        comb_s1<<<gl, 64, 0, stream>>>(dcs, dch, order, lvl, pnorm,
                                       acc_h, acc_fc, acc_zc,
                                       csWio_o, NW + NW_CSWIO, csWum_o, NW + NW_CSWUM,
                                       NB + NB_CSBIO, NB + NB_CSBUM, px,
                                       HB, Call, chWh_o, NW + NW_CHWH, NB + NB_CHBH,
                                       qx, ZB, G, d_out, fcnt);
        comb_s2<<<gl, 64, 0, stream>>>(dcs, dch, order, lvl, pnorm,
                                       csWfz_o, NW + NW_CSWFZ, NB + NB_CSBFZ, px,
                                       acc_fc, acc_zc,
                                       ZB, qx, chWum_o, NW + NW_CHWUM, NB + NB_CHBUM,
                                       Call, HB, G, fcnt);
    }

    // brep
    k_maxA<<<64, 256, 0, stream>>>(HB, pmax);
    k_maxB<<<1, 512, 0, stream>>>(pmax, d_out, fcnt);
}

// Round 14
// 1407.181 us; speedup vs baseline: 1.1011x; 1.1011x over previous
//
#include <hip/hip_runtime.h>
#include <hip/hip_bf16.h>

typedef unsigned short u16;
typedef unsigned int u32;

#define NN 8192
#define PXC 2560
#define MAXD 36
#define GY 64

typedef __attribute__((ext_vector_type(8))) short bf16x8;
typedef __attribute__((ext_vector_type(4))) float f32x4;

// ---------------- workspace layout (bytes) ----------------
static constexpr size_t SZ_PX  = (size_t)(NN + 1) * PXC * 2;
static constexpr size_t SZ_ACC = (size_t)(NN + 1) * 512 * 4;
static constexpr size_t SZ_HB  = (size_t)(NN + 1) * 512 * 2;
static constexpr size_t SZ_G   = (size_t)(NN + 1) * 1536 * 4;
static constexpr size_t SZ_NW  = (size_t)5242880 * 2;

static constexpr size_t OFF_PX    = 0;
static constexpr size_t OFF_QX    = OFF_PX + SZ_PX;
static constexpr size_t OFF_ACCH  = OFF_QX + SZ_PX;
static constexpr size_t OFF_ACCF  = OFF_ACCH + SZ_ACC;
static constexpr size_t OFF_ACCZ  = OFF_ACCF + SZ_ACC;
static constexpr size_t OFF_C     = OFF_ACCZ + SZ_ACC;         // c_all (chain), f32
static constexpr size_t OFF_HB    = OFF_C + SZ_ACC;            // h_all (chain), bf16
static constexpr size_t OFF_ZB    = OFF_HB + SZ_HB;            // chain ZB, bf16
static constexpr size_t OFF_G     = OFF_ZB + SZ_HB;            // per-node scratch / transient normalized inputs
static constexpr size_t OFF_NW    = OFF_G + SZ_G;
static constexpr size_t OFF_DEPTH = OFF_NW + SZ_NW;
static constexpr size_t OFF_ORDER = OFF_DEPTH + (size_t)NN * 4;
static constexpr size_t OFF_MISC  = OFF_ORDER + (size_t)NN * 4;
static constexpr size_t OFF_LVL   = OFF_MISC + 1024;
static constexpr size_t OFF_NB    = OFF_LVL + 512;
static constexpr size_t OFF_PN    = OFF_NB + 20480;
static constexpr size_t OFF_PMAX  = OFF_PN + (size_t)NN * 4;
static constexpr size_t WS_TOTAL  = OFF_PMAX + (size_t)128 * 512 * 4;

#define NW_CSWX  0
#define NW_CHWX  1310720
#define NW_CSWIO 2621440
#define NW_CSWFZ 3145728
#define NW_CSWUM 3670016
#define NW_CHWH  3932160
#define NW_CHWUM 4980736

#define NB_CSBX  0
#define NB_CSBIO 2560
#define NB_CSBFZ 3584
#define NB_CSBUM 4608
#define NB_CHBX  5120
#define NB_CHBH  7680
#define NB_CHBUM 9728

// ---------------- helpers ----------------
__device__ __forceinline__ float bfu(u16 u) { return __uint_as_float(((u32)u) << 16); }
__device__ __forceinline__ u16 f2bf(float f) {
    u32 u = __float_as_uint(f);
    u += 0x7fffu + ((u >> 16) & 1u);
    return (u16)(u >> 16);
}
__device__ __forceinline__ float sigf(float x) {
    x = fminf(fmaxf(x, -30.f), 30.f);
    return 1.f / (1.f + __expf(-x));
}
__device__ __forceinline__ float tanhq(float x) {
    x = fminf(fmaxf(x, -15.f), 15.f);
    return 1.f - 2.f / (__expf(2.f * x) + 1.f);
}
__device__ __forceinline__ bf16x8 cvt8(const float* p) {
    float4 a = *(const float4*)p;
    float4 b = *(const float4*)(p + 4);
    union { u32 u[4]; bf16x8 v; } r;
    r.u[0] = ((__float_as_uint(a.x) + 0x8000u) >> 16) | ((__float_as_uint(a.y) + 0x8000u) & 0xffff0000u);
    r.u[1] = ((__float_as_uint(a.z) + 0x8000u) >> 16) | ((__float_as_uint(a.w) + 0x8000u) & 0xffff0000u);
    r.u[2] = ((__float_as_uint(b.x) + 0x8000u) >> 16) | ((__float_as_uint(b.y) + 0x8000u) & 0xffff0000u);
    r.u[3] = ((__float_as_uint(b.z) + 0x8000u) >> 16) | ((__float_as_uint(b.w) + 0x8000u) & 0xffff0000u);
    return r.v;
}

// per-node scratch (G region, 1536 f32/node):
// cs: c -> f32 [n*1536 .. +512) ; h -> bf16 at u16 idx [n*3072+1024 .. +512)
// ch: si/so/sf -> f32 [n*1536 + {0,512,1024})

// ---------------- dtype detection ----------------
__global__ void k_detect(const u32* __restrict__ fin, const u32* __restrict__ pin,
                         int* __restrict__ fcnt, int* __restrict__ pcnt) {
    int i = blockIdx.x * 256 + threadIdx.x;
    if (i < 4096) {
        u32 w = fin[i];
        int e = (w >> 7) & 0xFF;
        if (w != 0u && e >= 0x70 && e <= 0x8F) atomicAdd(fcnt, 1);
    }
    if (i >= 1 && i < 4096) {
        if (pin[2 * i - 1] != 0u) atomicAdd(pcnt, 1);
    }
}

// fused: parent normalize + depth chase + sentinel-row init
__global__ void k_pnorm_depth(const u32* __restrict__ pin, const int* __restrict__ pcnt,
                              int* __restrict__ pnorm, int* __restrict__ depth,
                              u16* __restrict__ HB, float* __restrict__ Call) {
    int i = blockIdx.x * 256 + threadIdx.x;
    if (i < 512) {
        HB[(size_t)NN * 512 + i] = 0;
        Call[(size_t)NN * 512 + i] = 0.f;
    }
    if (i >= NN) return;
    bool is64 = (*pcnt < 100);
    int p = (int)(is64 ? pin[2 * i] : pin[i]);
    pnorm[i] = p;
    int d = 0;
    while (p != NN && p >= 0 && p < NN && d < 9000) {
        d++;
        p = (int)(is64 ? pin[2 * p] : pin[p]);
    }
    depth[i] = d;
}

// fused hist + scan + scatter, single block
__global__ __launch_bounds__(1024) void k_levels(const int* __restrict__ depth,
                                                 int* __restrict__ lvl, int* __restrict__ order) {
    __shared__ int cnts[64];
    __shared__ int cur[64];
    int t = threadIdx.x;
    if (t < 64) cnts[t] = 0;
    __syncthreads();
    for (int i = t; i < NN; i += 1024) {
        int d = depth[i]; if (d > 63) d = 63;
        atomicAdd(&cnts[d], 1);
    }
    __syncthreads();
    if (t == 0) {
        int s = 0; lvl[0] = 0;
        for (int d = 0; d < 64; ++d) { cur[d] = s; s += cnts[d]; lvl[d + 1] = s; }
    }
    __syncthreads();
    for (int i = t; i < NN; i += 1024) {
        int d = depth[i]; if (d > 63) d = 63;
        int pos = atomicAdd(&cur[d], 1);
        order[pos] = i;
    }
}

struct NormSrcs { const void* p[15]; };
// segs 0-7 (inputs + weights) only needed when f32; segs 8-14 (biases) always
__global__ __launch_bounds__(256) void k_norm_all(NormSrcs s, u16* __restrict__ NGI,
                                                  u16* __restrict__ NW, u16* __restrict__ NB,
                                                  const int* __restrict__ fcnt) {
    const int cum[16] = {0, 1048576, 1376256, 1703936, 1835008, 1966080, 2031616, 2293760,
                         2359296, 2359936, 2360192, 2360448, 2360576, 2361216, 2361728, 2361856};
    const int dof[15] = {0, NW_CSWX / 4, NW_CHWX / 4, NW_CSWIO / 4, NW_CSWFZ / 4, NW_CSWUM / 4,
                         NW_CHWH / 4, NW_CHWUM / 4, NB_CSBX / 4, NB_CSBIO / 4, NB_CSBFZ / 4,
                         NB_CSBUM / 4, NB_CHBX / 4, NB_CHBH / 4, NB_CHBUM / 4};
    bool isbf = (*fcnt > 2048);
    int total = 2361856;
    int istart = isbf ? cum[8] : 0;       // bf16: only biases need copying
    for (int i = istart + blockIdx.x * 256 + threadIdx.x; i < total; i += gridDim.x * 256) {
        int seg = 0;
#pragma unroll
        for (int k = 1; k < 15; ++k) if (i >= cum[k]) seg = k;
        int off = i - cum[seg];
        u16* dbase = (seg == 0) ? NGI : (seg < 8 ? NW : NB);
        ushort4* dst = (ushort4*)dbase + dof[seg] + off;
        if (isbf) {
            *dst = ((const ushort4*)s.p[seg])[off];
        } else {
            float4 v = ((const float4*)s.p[seg])[off];
            ushort4 o; o.x = f2bf(v.x); o.y = f2bf(v.y); o.z = f2bf(v.z); o.w = f2bf(v.w);
            *dst = o;
        }
    }
}

// ---------------- input-projection GEMM: grid (10, 128, 2), A-tile staged in LDS ----------------
#define ASTR 528   // u16 row stride: 1056B (16B-aligned), 264 dw -> 4-way bank alias only
__global__ __launch_bounds__(256) void k_gemm_in(
    const u16* __restrict__ Ao, const u16* __restrict__ An,
    const u16* __restrict__ Wcs_o, const u16* __restrict__ Wcs_n,
    const u16* __restrict__ Wch_o, const u16* __restrict__ Wch_n,
    const u16* __restrict__ bcs, const u16* __restrict__ bch,
    u16* __restrict__ Ccs, u16* __restrict__ Cch,
    const int* __restrict__ fcnt)
{
    __shared__ __align__(16) u16 AS[64 * ASTR];
    bool isbf = (*fcnt > 2048);
    int z = blockIdx.z;
    const u16* A = isbf ? Ao : An;
    const u16* W = z ? (isbf ? Wch_o : Wch_n) : (isbf ? Wcs_o : Wcs_n);
    const u16* bias = z ? bch : bcs;
    u16* C = z ? Cch : Ccs;

    int m0 = blockIdx.y * 64;
    // cooperative A-tile load: 64 rows x 512 cols (each thread 16 x 16B chunks)
    for (int e = threadIdx.x; e < 64 * 64; e += 256) {
        int row = e >> 6, c8 = e & 63;
        *(uint4*)&AS[row * ASTR + c8 * 8] = *(const uint4*)(A + (size_t)(m0 + row) * 512 + c8 * 8);
    }
    __syncthreads();

    int wv = threadIdx.x >> 6;
    int lane = threadIdx.x & 63;
    int r = lane & 15, q = lane >> 4;
    int n0 = blockIdx.x * 256 + wv * 64;
    const u16* pb[4];
#pragma unroll
    for (int jt = 0; jt < 4; ++jt) pb[jt] = W + (size_t)(n0 + jt * 16 + r) * 512 + q * 8;
    f32x4 acc[4][4] = {};
#pragma unroll 2
    for (int k0 = 0; k0 < 512; k0 += 32) {
        bf16x8 a[4], b[4];
#pragma unroll
        for (int mi = 0; mi < 4; ++mi)
            a[mi] = *(const bf16x8*)&AS[(mi * 16 + r) * ASTR + k0 + q * 8];
#pragma unroll
        for (int jt = 0; jt < 4; ++jt) b[jt] = *(const bf16x8*)(pb[jt] + k0);
#pragma unroll
        for (int mi = 0; mi < 4; ++mi)
#pragma unroll
            for (int jt = 0; jt < 4; ++jt)
                acc[mi][jt] = __builtin_amdgcn_mfma_f32_16x16x32_bf16(a[mi], b[jt], acc[mi][jt], 0, 0, 0);
    }
#pragma unroll
    for (int jt = 0; jt < 4; ++jt) {
        int c = n0 + jt * 16 + r;
        float bv = bfu(bias[c]);
#pragma unroll
        for (int mi = 0; mi < 4; ++mi) {
            size_t b0 = (size_t)(m0 + mi * 16 + q * 4) * PXC + c;
#pragma unroll
            for (int i = 0; i < 4; ++i)
                C[b0 + (size_t)i * PXC] = f2bf(acc[mi][jt][i] + bv);
        }
    }
}

// ---------------- combined phase-1: grid (32, GY, 2), plane = blockIdx.z (round-12 config) ----------------
__global__ __launch_bounds__(64) void comb_s1(
    int dcs, int dch,
    const int* __restrict__ order, const int* __restrict__ lvl, const int* __restrict__ parent,
    float* acc_h, const float* __restrict__ acc_fc, const float* __restrict__ acc_zc,
    const u16* __restrict__ Wio_o, const u16* __restrict__ Wio_n,
    const u16* __restrict__ Wum_o, const u16* __restrict__ Wum_n,
    const u16* __restrict__ bio, const u16* __restrict__ bum,
    const u16* __restrict__ px,
    const u16* __restrict__ HB, const float* __restrict__ Call,
    const u16* __restrict__ Wh_o, const u16* __restrict__ Wh_n,
    const u16* __restrict__ bh,
    const u16* __restrict__ qx, u16* __restrict__ ZB,
    float* __restrict__ G,
    void* __restrict__ outv, const int* __restrict__ fcnt)
{
    bool isbf = (*fcnt > 2048);
    int lane = threadIdx.x;
    int r = lane & 15, q = lane >> 4;
    int cg = blockIdx.x;
    int c0 = cg * 16;
    int col = c0 + r;
    u16* Gh = (u16*)G;

    if (blockIdx.z == 0) {
        int d = dcs;
        int start = lvl[d], cnt = lvl[d + 1] - start;
        if (cnt <= 0) return;
        int ntiles = (cnt + 15) >> 4;
        const u16* Wio = isbf ? Wio_o : Wio_n;
        const u16* Wum = isbf ? Wum_o : Wum_n;
        const u16* pbi = Wio + (size_t)(c0 + r) * 512 + q * 8;
        const u16* pbo = Wio + (size_t)(512 + c0 + r) * 512 + q * 8;
        const u16* pbu = Wum + (size_t)(c0 + r) * 512 + q * 8;
        for (int tile = blockIdx.y; tile < ntiles; tile += GY) {
            int tr = tile * 16 + r;
            int nodeR = (tr < cnt) ? order[start + tr] : NN;
            const float* pah = acc_h + (size_t)nodeR * 512 + q * 8;
            const float* paz = acc_zc + (size_t)nodeR * 512 + q * 8;
            f32x4 ai = {}, ao = {}, au = {};
#pragma unroll 4
            for (int ko = 0; ko < 512; ko += 32) {
                bf16x8 a_h = cvt8(pah + ko);
                bf16x8 a_z = cvt8(paz + ko);
                ai = __builtin_amdgcn_mfma_f32_16x16x32_bf16(a_h, *(const bf16x8*)(pbi + ko), ai, 0, 0, 0);
                ao = __builtin_amdgcn_mfma_f32_16x16x32_bf16(a_h, *(const bf16x8*)(pbo + ko), ao, 0, 0, 0);
                au = __builtin_amdgcn_mfma_f32_16x16x32_bf16(a_z, *(const bf16x8*)(pbu + ko), au, 0, 0, 0);
            }
            float bi_ = bfu(bio[col]), bo_ = bfu(bio[512 + col]), bu_ = bfu(bum[col]);
#pragma unroll
            for (int i2 = 0; i2 < 4; ++i2) {
                int ti = tile * 16 + q * 4 + i2;
                if (ti >= cnt) continue;
                int ni = order[start + ti];
                int p = parent[ni];
                size_t pxb = (size_t)ni * PXC, nb = (size_t)ni * 512;
                float ig = sigf(bfu(px[pxb + col]) + ai[i2] + bi_);
                float og = sigf(bfu(px[pxb + 1024 + col]) + ao[i2] + bo_);
                float uu = tanhq(bfu(px[pxb + 2048 + col]) + au[i2] + bu_);
                float cc = ig * uu + acc_fc[nb + col];
                float h = og * tanhq(cc);
                G[(size_t)ni * 1536 + col] = cc;
                Gh[(size_t)ni * 3072 + 1024 + col] = f2bf(h);
                atomicAdd(&acc_h[(size_t)p * 512 + col], h);
                if (ni == 0) {
                    if (isbf) ((u16*)outv)[col] = f2bf(h);
                    else ((float*)outv)[col] = h;
                }
            }
        }
    } else {
        int d = dch;
        int start = lvl[d], cnt = lvl[d + 1] - start;
        if (cnt <= 0) return;
        int ntiles = (cnt + 15) >> 4;
        const u16* Wh = isbf ? Wh_o : Wh_n;
        const u16* pbi = Wh + (size_t)(c0 + r) * 512 + q * 8;
        const u16* pbo = Wh + (size_t)(512 + c0 + r) * 512 + q * 8;
        const u16* pbf = Wh + (size_t)(1024 + c0 + r) * 512 + q * 8;
        const u16* pbz = Wh + (size_t)(1536 + c0 + r) * 512 + q * 8;
        for (int tile = blockIdx.y; tile < ntiles; tile += GY) {
            int tr = tile * 16 + r;
            int nod = (tr < cnt) ? order[start + tr] : -1;
            int prow = (nod < 0) ? NN : parent[nod];
            const u16* pa = HB + (size_t)prow * 512 + q * 8;
            f32x4 gi = {}, go = {}, gf = {}, gz = {};
#pragma unroll 4
            for (int ko = 0; ko < 512; ko += 32) {
                bf16x8 a = *(const bf16x8*)(pa + ko);
                gi = __builtin_amdgcn_mfma_f32_16x16x32_bf16(a, *(const bf16x8*)(pbi + ko), gi, 0, 0, 0);
                go = __builtin_amdgcn_mfma_f32_16x16x32_bf16(a, *(const bf16x8*)(pbo + ko), go, 0, 0, 0);
                gf = __builtin_amdgcn_mfma_f32_16x16x32_bf16(a, *(const bf16x8*)(pbf + ko), gf, 0, 0, 0);
                gz = __builtin_amdgcn_mfma_f32_16x16x32_bf16(a, *(const bf16x8*)(pbz + ko), gz, 0, 0, 0);
            }
            float bi_ = bfu(bh[col]), bo_ = bfu(bh[512 + col]);
            float bf_ = bfu(bh[1024 + col]), bz_ = bfu(bh[1536 + col]);
#pragma unroll
            for (int i2 = 0; i2 < 4; ++i2) {
                int ti = tile * 16 + q * 4 + i2;
                if (ti >= cnt) continue;
                int ni = order[start + ti];
                int p = parent[ni];
                size_t qb = (size_t)ni * PXC, gb = (size_t)ni * 1536, nb = (size_t)ni * 512;
                float si = sigf(bfu(qx[qb + col]) + gi[i2] + bi_);
                float so = sigf(bfu(qx[qb + 512 + col]) + go[i2] + bo_);
                float sf = sigf(bfu(qx[qb + 1024 + col]) + gf[i2] + bf_);
                float zg = sigf(bfu(qx[qb + 1536 + col]) + gz[i2] + bz_);
                G[gb + col] = si;
                G[gb + 512 + col] = so;
                G[gb + 1024 + col] = sf;
                ZB[nb + col] = f2bf(zg * tanhq(Call[(size_t)p * 512 + col]));
            }
        }
    }
}

// ---------------- combined phase-2 (K-split accumulator chains) ----------------
__global__ __launch_bounds__(64) void comb_s2(
    int dcs, int dch,
    const int* __restrict__ order, const int* __restrict__ lvl, const int* __restrict__ parent,
    const u16* __restrict__ Wfz_o, const u16* __restrict__ Wfz_n,
    const u16* __restrict__ bfz,
    const u16* __restrict__ px,
    float* __restrict__ acc_fc, float* __restrict__ acc_zc,
    const u16* __restrict__ ZB, const u16* __restrict__ qx,
    const u16* __restrict__ Wum_o, const u16* __restrict__ Wum_n,
    const u16* __restrict__ bum,
    float* __restrict__ Call, u16* __restrict__ HB,
    float* __restrict__ G, const int* __restrict__ fcnt)
{
    bool isbf = (*fcnt > 2048);
    int lane = threadIdx.x;
    int r = lane & 15, q = lane >> 4;
    int cg = blockIdx.x;
    int c0 = cg * 16;
    int col = c0 + r;
    const u16* Gh = (const u16*)G;

    if (blockIdx.z == 0) {
        int d = dcs;
        int start = lvl[d], cnt = lvl[d + 1] - start;
        if (cnt <= 0) return;
        int ntiles = (cnt + 15) >> 4;
        const u16* Wfz = isbf ? Wfz_o : Wfz_n;
        const u16* pbf = Wfz + (size_t)(c0 + r) * 512 + q * 8;
        const u16* pbz = Wfz + (size_t)(512 + c0 + r) * 512 + q * 8;
        for (int tile = blockIdx.y; tile < ntiles; tile += GY) {
            int tr = tile * 16 + r;
            int nodeR = (tr < cnt) ? order[start + tr] : NN;
            const u16* pa = Gh + (size_t)nodeR * 3072 + 1024 + q * 8;
            f32x4 af0 = {}, af1 = {}, az0 = {}, az1 = {};
#pragma unroll 4
            for (int ko = 0; ko < 256; ko += 32) {
                bf16x8 a0 = *(const bf16x8*)(pa + ko);
                bf16x8 a1 = *(const bf16x8*)(pa + 256 + ko);
                af0 = __builtin_amdgcn_mfma_f32_16x16x32_bf16(a0, *(const bf16x8*)(pbf + ko), af0, 0, 0, 0);
                az0 = __builtin_amdgcn_mfma_f32_16x16x32_bf16(a0, *(const bf16x8*)(pbz + ko), az0, 0, 0, 0);
                af1 = __builtin_amdgcn_mfma_f32_16x16x32_bf16(a1, *(const bf16x8*)(pbf + 256 + ko), af1, 0, 0, 0);
                az1 = __builtin_amdgcn_mfma_f32_16x16x32_bf16(a1, *(const bf16x8*)(pbz + 256 + ko), az1, 0, 0, 0);
            }
            f32x4 af = af0 + af1, az = az0 + az1;
            float bf_ = bfu(bfz[col]), bz_ = bfu(bfz[512 + col]);
#pragma unroll
            for (int i2 = 0; i2 < 4; ++i2) {
                int ti = tile * 16 + q * 4 + i2;
                if (ti >= cnt) continue;
                int ni = order[start + ti];
                int p = parent[ni];
                size_t pb = (size_t)p * 512, ppx = (size_t)p * PXC;
                float cT = G[(size_t)ni * 1536 + col];
                float f = sigf(bfu(px[ppx + 512 + col]) + af[i2] + bf_);
                atomicAdd(&acc_fc[pb + col], f * cT);
                float zf = sigf(bfu(px[ppx + 1536 + col]) + az[i2] + bz_);
                atomicAdd(&acc_zc[pb + col], zf * tanhq(cT));
            }
        }
    } else {
        int d = dch;
        int start = lvl[d], cnt = lvl[d + 1] - start;
        if (cnt <= 0) return;
        int ntiles = (cnt + 15) >> 4;
        const u16* Wum = isbf ? Wum_o : Wum_n;
        const u16* pbu = Wum + (size_t)(c0 + r) * 512 + q * 8;
        for (int tile = blockIdx.y; tile < ntiles; tile += GY) {
            int tr = tile * 16 + r;
            int nodeR = (tr < cnt) ? order[start + tr] : NN;
            const u16* pa = ZB + (size_t)nodeR * 512 + q * 8;
            f32x4 a0 = {}, a1 = {}, a2 = {}, a3 = {};
#pragma unroll 4
            for (int ko = 0; ko < 128; ko += 32) {
                a0 = __builtin_amdgcn_mfma_f32_16x16x32_bf16(*(const bf16x8*)(pa + ko),
                                                             *(const bf16x8*)(pbu + ko), a0, 0, 0, 0);
                a1 = __builtin_amdgcn_mfma_f32_16x16x32_bf16(*(const bf16x8*)(pa + 128 + ko),
                                                             *(const bf16x8*)(pbu + 128 + ko), a1, 0, 0, 0);
                a2 = __builtin_amdgcn_mfma_f32_16x16x32_bf16(*(const bf16x8*)(pa + 256 + ko),
                                                             *(const bf16x8*)(pbu + 256 + ko), a2, 0, 0, 0);
                a3 = __builtin_amdgcn_mfma_f32_16x16x32_bf16(*(const bf16x8*)(pa + 384 + ko),
                                                             *(const bf16x8*)(pbu + 384 + ko), a3, 0, 0, 0);
            }
            f32x4 au = (a0 + a1) + (a2 + a3);
            float bu_ = bfu(bum[col]);
#pragma unroll
            for (int i2 = 0; i2 < 4; ++i2) {
                int ti = tile * 16 + q * 4 + i2;
                if (ti >= cnt) continue;
                int ni = order[start + ti];
                int p = parent[ni];
                size_t qb = (size_t)ni * PXC, gb = (size_t)ni * 1536, nb = (size_t)ni * 512;
                float uu = tanhq(bfu(qx[qb + 2048 + col]) + au[i2] + bu_);
                float si = G[gb + col];
                float so = G[gb + 512 + col];
                float sf = G[gb + 1024 + col];
                float pc = Call[(size_t)p * 512 + col];
                float cc = si * uu + sf * pc;
                float h = so * tanhq(cc);
                Call[nb + col] = cc;
                HB[nb + col] = f2bf(h);
            }
        }
    }
}

// ---------------- final max reduce ----------------
__global__ __launch_bounds__(256) void k_maxA(const u16* __restrict__ HB, float* __restrict__ pmax) {
    int b = blockIdx.x, t = threadIdx.x;
    float m1 = -1e30f, m2 = -1e30f;
    for (int rr = b * 128; rr < b * 128 + 128; ++rr) {
        m1 = fmaxf(m1, bfu(HB[(size_t)rr * 512 + t]));
        m2 = fmaxf(m2, bfu(HB[(size_t)rr * 512 + t + 256]));
    }
    pmax[(size_t)b * 512 + t] = m1; pmax[(size_t)b * 512 + t + 256] = m2;
}
__global__ void k_maxB(const float* __restrict__ pmax, void* __restrict__ outv,
                       const int* __restrict__ fcnt) {
    int j = threadIdx.x;
    float m = -1e30f;
    for (int b = 0; b < 64; ++b) m = fmaxf(m, pmax[(size_t)b * 512 + j]);
    bool isbf = (*fcnt > 2048);
    if (isbf) ((u16*)outv)[512 + j] = f2bf(m);
    else ((float*)outv)[512 + j] = m;
}

__global__ void k_wsfail(u16* out) {
    int i = blockIdx.x * 256 + threadIdx.x;
    if (i < 1024) out[i] = f2bf(12345.f);
}

// ---------------- launch ----------------
extern "C" void kernel_launch(void* const* d_in, const int* in_sizes, int n_in,
                              void* d_out, int out_size, void* d_ws, size_t ws_size,
                              hipStream_t stream) {
    char* base = (char*)d_ws;
    u16* px = (u16*)(base + OFF_PX);
    u16* qx = (u16*)(base + OFF_QX);
    float* acc_h = (float*)(base + OFF_ACCH);
    float* acc_fc = (float*)(base + OFF_ACCF);
    float* acc_zc = (float*)(base + OFF_ACCZ);
    float* Call = (float*)(base + OFF_C);
    u16* HB = (u16*)(base + OFF_HB);
    u16* ZB = (u16*)(base + OFF_ZB);
    float* G = (float*)(base + OFF_G);
    u16* NGI = (u16*)(base + OFF_G);
    u16* NW = (u16*)(base + OFF_NW);
    int* depth = (int*)(base + OFF_DEPTH);
    int* order = (int*)(base + OFF_ORDER);
    int* counts = (int*)(base + OFF_MISC);
    int* fcnt = counts + 128;
    int* pcnt = counts + 129;
    int* lvl = (int*)(base + OFF_LVL);
    u16* NB = (u16*)(base + OFF_NB);
    int* pnorm = (int*)(base + OFF_PN);
    float* pmax = (float*)(base + OFF_PMAX);

    const u16* in_bf   = (const u16*)d_in[0];
    const u16* csWx_o  = (const u16*)d_in[2];
    const u16* csWio_o = (const u16*)d_in[4];
    const u16* csWfz_o = (const u16*)d_in[6];
    const u16* csWum_o = (const u16*)d_in[8];
    const u16* chWx_o  = (const u16*)d_in[10];
    const u16* chWh_o  = (const u16*)d_in[12];
    const u16* chWum_o = (const u16*)d_in[14];

    if (ws_size < WS_TOTAL) { k_wsfail<<<4, 256, 0, stream>>>((u16*)d_out); return; }

    hipMemsetAsync(base + OFF_MISC, 0, 1024, stream);
    hipMemsetAsync(base + OFF_ACCH, 0, 3 * SZ_ACC, stream);   // acc_h/fc/zc (+ sentinel rows)

    // dtype detect + fused setup
    k_detect<<<16, 256, 0, stream>>>((const u32*)d_in[0], (const u32*)d_in[1], fcnt, pcnt);
    k_pnorm_depth<<<32, 256, 0, stream>>>((const u32*)d_in[1], pcnt, pnorm, depth, HB, Call);
    k_levels<<<1, 1024, 0, stream>>>(depth, lvl, order);

    NormSrcs srcs;
    srcs.p[0] = d_in[0];  srcs.p[1] = d_in[2];  srcs.p[2] = d_in[10]; srcs.p[3] = d_in[4];
    srcs.p[4] = d_in[6];  srcs.p[5] = d_in[8];  srcs.p[6] = d_in[12]; srcs.p[7] = d_in[14];
    srcs.p[8] = d_in[3];  srcs.p[9] = d_in[5];  srcs.p[10] = d_in[7]; srcs.p[11] = d_in[9];
    srcs.p[12] = d_in[11]; srcs.p[13] = d_in[13]; srcs.p[14] = d_in[15];
    k_norm_all<<<2048, 256, 0, stream>>>(srcs, NGI, NW, NB, fcnt);

    // input projections — A-tile in LDS, 64m x 256n per block (round-13 winner)
    dim3 gg(PXC / 256, NN / 64, 2);
    k_gemm_in<<<gg, 256, 0, stream>>>(in_bf, NGI,
                                      csWx_o, NW + NW_CSWX, chWx_o, NW + NW_CHWX,
                                      NB + NB_CSBX, NB + NB_CHBX, px, qx, fcnt);

    // fused levels: dispatch i runs cs level (MAXD-1-i) and ch level (i) (round-12 config)
    dim3 gl(32, GY, 2);
    for (int i = 0; i < MAXD; ++i) {
        int dcs = MAXD - 1 - i, dch = i;
        comb_s1<<<gl, 64, 0, stream>>>(dcs, dch, order, lvl, pnorm,
                                       acc_h, acc_fc, acc_zc,
                                       csWio_o, NW + NW_CSWIO, csWum_o, NW + NW_CSWUM,
                                       NB + NB_CSBIO, NB + NB_CSBUM, px,
                                       HB, Call, chWh_o, NW + NW_CHWH, NB + NB_CHBH,
                                       qx, ZB, G, d_out, fcnt);
        comb_s2<<<gl, 64, 0, stream>>>(dcs, dch, order, lvl, pnorm,
                                       csWfz_o, NW + NW_CSWFZ, NB + NB_CSBFZ, px,
                                       acc_fc, acc_zc,
                                       ZB, qx, chWum_o, NW + NW_CHWUM, NB + NB_CHBUM,
                                       Call, HB, G, fcnt);
    }

    // brep
    k_maxA<<<64, 256, 0, stream>>>(HB, pmax);
    k_maxB<<<1, 512, 0, stream>>>(pmax, d_out, fcnt);
}